// Round 3
// baseline (414.604 us; speedup 1.0000x reference)
//
#include <hip/hip_runtime.h>
#include <math.h>

#define B_CUR 4096
#define N_TOT 8192
#define C_F   256
#define C_TOT 288
#define KSEL  16
#define NTILE 64    // 8192 / 128

typedef unsigned short u16;
typedef __attribute__((ext_vector_type(8))) short short8;
typedef __attribute__((ext_vector_type(4))) float floatx4;
typedef __attribute__((ext_vector_type(4))) float f32x4;

__device__ inline float bf2f(u16 v) {
  union { unsigned int u; float f; } x; x.u = ((unsigned int)v) << 16; return x.f;
}
__device__ inline u16 f2bf(float f) {
  union { float f; unsigned int u; } x; x.f = f;
  unsigned int u = x.u;
  u += ((u >> 16) & 1u) + 0x7FFFu;   // RNE
  return (u16)(u >> 16);
}

#define GLD_LDS16(g, l) __builtin_amdgcn_global_load_lds(                      \
    (const __attribute__((address_space(1))) unsigned int*)(g),                \
    (__attribute__((address_space(3))) unsigned int*)(l), 16, 0, 0)

// K1 (fused): per wave = one row. Feature normalize (64 lanes) + PE (32 lanes).
__global__ __launch_bounds__(256) void k_prep(
    const float* __restrict__ feats, const float* __restrict__ hfeats,
    const float* __restrict__ coords, const float* __restrict__ hcoords,
    u16* __restrict__ Zb, float* __restrict__ out_nf) {
  int wave = threadIdx.x >> 6;
  int lane = threadIdx.x & 63;
  int row  = blockIdx.x * 4 + wave;
  const float* src = (row < B_CUR) ? (feats + (size_t)row * C_F)
                                   : (hfeats + (size_t)(row - B_CUR) * C_F);
  int c0 = lane * 4;
  f32x4 raw = *(const f32x4*)(src + c0);
  float ss = raw[0]*raw[0] + raw[1]*raw[1] + raw[2]*raw[2] + raw[3]*raw[3];
  #pragma unroll
  for (int m = 32; m; m >>= 1) ss += __shfl_xor(ss, m, 64);
  float scale = 0.97467943448089633f / fmaxf(sqrtf(ss), 1e-12f);   // sqrt(0.95)
  ushort4 o;
  o.x = f2bf(raw[0]*scale); o.y = f2bf(raw[1]*scale);
  o.z = f2bf(raw[2]*scale); o.w = f2bf(raw[3]*scale);
  *(ushort4*)(Zb + (size_t)row * C_TOT + c0) = o;
  // write-once, never re-read this pass: nontemporal keeps L3 for Zb/S
  __builtin_nontemporal_store(raw, (f32x4*)(out_nf + (size_t)row * C_F + c0));

  const float* csrc = (row < B_CUR) ? (coords + (size_t)row * 4)
                                    : (hcoords + (size_t)(row - B_CUR) * 4);
  int d = lane >> 3, sc = (lane >> 2) & 1, f = lane & 3;
  float c = csrc[d & 3];
  float ang = c * 6.283185307179586f * (float)(1 << f);
  float pe = sc ? cosf(ang) : sinf(ang);
  float p2 = pe * pe;
  #pragma unroll
  for (int m = 16; m; m >>= 1) p2 += __shfl_xor(p2, m, 64);
  float pscale = 0.22360679774997896f / fmaxf(sqrtf(p2), 1e-12f); // sqrt(0.05)
  if (lane < 32) Zb[(size_t)row * C_TOT + C_F + lane] = f2bf(pe * pscale);
}

// K3: S = Zb Zb^T, symmetric: upper-triangle tiles only, mirrored epilogue.
// LDS stride 96 u16 = 192 B: the 64-lane ds_read_b128 pattern lands on 8
// distinct 16B slots tiling all 32 banks (8 lanes/slot time-multiplexed
// perfectly) -> minimum 8 cycles, conflict-free. (Stride-104 experiment was
// neutral-to-negative: reverted.)
// NEW: epilogue also emits per-row tile-max smax[row][tile] (bf16) so k_topk
// can prune ~3/4 of its S reads.
#define EP_STRIDE 136
__global__ __launch_bounds__(256) void k_gemm_mfma(const u16* __restrict__ Zb,
                                                   u16* __restrict__ adj16,
                                                   u16* __restrict__ smax) {
  __shared__ __align__(16) u16 smem[2 * 128 * 96];     // 49152 B
  u16* As = smem;
  u16* Bs = smem + 128 * 96;
  int tid  = threadIdx.x;

  int t = blockIdx.x;
  int bi = (int)floorf(((2.0f*NTILE + 1.0f) -
            sqrtf((float)((2*NTILE+1)*(2*NTILE+1)) - 8.0f*(float)t)) * 0.5f);
  if (bi < 0) bi = 0; if (bi > NTILE-1) bi = NTILE-1;
  while (bi > 0 && t < bi*NTILE - bi*(bi-1)/2) --bi;
  while (bi < NTILE-1 && t >= (bi+1)*NTILE - (bi+1)*bi/2) ++bi;
  int bj = bi + (t - (bi*NTILE - bi*(bi-1)/2));

  int wave = tid >> 6, lane = tid & 63;
  int quad = lane >> 4, l16 = lane & 15;
  int m0w  = (wave >> 1) * 64;
  int n0w  = (wave & 1) * 64;
  int i0   = bi * 128, j0 = bj * 128;

  floatx4 acc[4][4];
  #pragma unroll
  for (int a = 0; a < 4; ++a)
    #pragma unroll
    for (int b = 0; b < 4; ++b) acc[a][b] = (floatx4){0.f, 0.f, 0.f, 0.f};

  for (int kt = 0; kt < C_TOT; kt += 96) {
    #pragma unroll
    for (int it = 0; it < 6; ++it) {
      int s   = it * 256 + tid;
      int row = s / 12, seg = s % 12;
      const u16* ga = Zb + (size_t)(i0 + row) * C_TOT + kt + seg * 8;
      const u16* gb = Zb + (size_t)(j0 + row) * C_TOT + kt + seg * 8;
      GLD_LDS16(ga, As + s * 8);
      GLD_LDS16(gb, Bs + s * 8);
    }
    __builtin_amdgcn_s_waitcnt(0);
    __syncthreads();
    #pragma unroll
    for (int ks = 0; ks < 3; ++ks) {
      short8 af[4], bf[4];
      #pragma unroll
      for (int mi = 0; mi < 4; ++mi)
        af[mi] = *(const short8*)(&As[(m0w + mi*16 + l16) * 96 + ks*32 + quad*8]);
      #pragma unroll
      for (int ni = 0; ni < 4; ++ni)
        bf[ni] = *(const short8*)(&Bs[(n0w + ni*16 + l16) * 96 + ks*32 + quad*8]);
      #pragma unroll
      for (int mi = 0; mi < 4; ++mi)
        #pragma unroll
        for (int ni = 0; ni < 4; ++ni)
          acc[mi][ni] = __builtin_amdgcn_mfma_f32_16x16x32_bf16(
              af[mi], bf[ni], acc[mi][ni], 0, 0, 0);
    }
    __syncthreads();
  }

  float w = ((bi < 32) != (bj < 32)) ? 0.5f : 1.0f;

  #pragma unroll
  for (int mi = 0; mi < 4; ++mi) {
    #pragma unroll
    for (int ni = 0; ni < 4; ++ni) {
      int col = n0w + ni * 16 + l16;
      #pragma unroll
      for (int rg = 0; rg < 4; ++rg) {
        int row = m0w + mi * 16 + quad * 4 + rg;
        smem[row * EP_STRIDE + col] = f2bf(acc[mi][ni][rg] * w);
      }
    }
  }
  __syncthreads();
  // per-row max of this tile (2 threads/row); exact: values already bf16
  {
    int row = tid >> 1, half = tid & 1;
    const u16* rp = &smem[row * EP_STRIDE + half * 64];   // 272B row pitch: 16B-aligned
    float mx = -3.0e38f;
    #pragma unroll
    for (int q = 0; q < 8; ++q) {
      uint4 v = *(const uint4*)(rp + q * 8);
      const u16* e = (const u16*)&v;
      #pragma unroll
      for (int z = 0; z < 8; ++z) mx = fmaxf(mx, bf2f(e[z]));
    }
    float o2 = __shfl_xor(mx, 1, 64);
    mx = fmaxf(mx, o2);
    if (half == 0) smax[(size_t)(i0 + row) * 64 + bj] = f2bf(mx);
  }
  #pragma unroll
  for (int it = 0; it < 8; ++it) {
    int idx = it * 256 + tid;
    int row = idx >> 4, l = idx & 15;
    uint4 v = *(const uint4*)(&smem[row * EP_STRIDE + l * 8]);
    *(uint4*)(&adj16[(size_t)(i0 + row) * 16384 + j0 + l * 8]) = v;
  }

  if (bi != bj) {
    __syncthreads();
    #pragma unroll
    for (int mi = 0; mi < 4; ++mi) {
      #pragma unroll
      for (int ni = 0; ni < 4; ++ni) {
        int col = n0w + ni * 16 + l16;
        #pragma unroll
        for (int rg = 0; rg < 4; ++rg) {
          int row = m0w + mi * 16 + quad * 4 + rg;
          smem[col * EP_STRIDE + row] = f2bf(acc[mi][ni][rg] * w);
        }
      }
    }
    __syncthreads();
    // mirror rows are the j-panel; their tile index is bi
    {
      int row = tid >> 1, half = tid & 1;
      const u16* rp = &smem[row * EP_STRIDE + half * 64];
      float mx = -3.0e38f;
      #pragma unroll
      for (int q = 0; q < 8; ++q) {
        uint4 v = *(const uint4*)(rp + q * 8);
        const u16* e = (const u16*)&v;
        #pragma unroll
        for (int z = 0; z < 8; ++z) mx = fmaxf(mx, bf2f(e[z]));
      }
      float o2 = __shfl_xor(mx, 1, 64);
      mx = fmaxf(mx, o2);
      if (half == 0) smax[(size_t)(j0 + row) * 64 + bi] = f2bf(mx);
    }
    #pragma unroll
    for (int it = 0; it < 8; ++it) {
      int idx = it * 256 + tid;
      int row = idx >> 4, l = idx & 15;
      uint4 v = *(const uint4*)(&smem[row * EP_STRIDE + l * 8]);
      *(uint4*)(&adj16[(size_t)(j0 + row) * 16384 + i0 + l * 8]) = v;
    }
  }
}

// K4: per-row top-16, register-resident selection, TILE-PRUNED reads.
//     T = 16th-largest tile-max (tie-conservative lower bound): tiles with
//     max < T provably contain no top-16 member -> skip their loads (~3/4).
//     adj16/adj ALIAS: no __restrict__ on them; __syncthreads separates reads
//     (into registers) from the nontemporal zero-stores.
__global__ __launch_bounds__(256) void k_topk(
    const u16* adj16, float* adj, const u16* __restrict__ smax,
    int* __restrict__ topk_idx, float* __restrict__ topk_val,
    float* __restrict__ deg_out) {
  __shared__ unsigned int cand[64];
  __shared__ float s_diag;
  __shared__ u16 s_surv[64];
  int r = blockIdx.x;
  int t = threadIdx.x;
  int wave = t >> 6, lane = t & 63;
  const u16* rowp = adj16 + (size_t)r * 16384;

  // 0) wave 0: tile-max pruning threshold T (16th-largest, ties conservative)
  if (t == 0) s_diag = bf2f(rowp[r]);
  if (t < 64) {
    u16 tm = smax[(size_t)r * 64 + t];
    unsigned int s16 = (tm & 0x8000u) ? ((unsigned int)tm ^ 0xFFFFu)
                                      : ((unsigned int)tm | 0x8000u);
    unsigned int m = s16, T = 0;
    for (int it = 0; it < KSEL; ++it) {
      unsigned int wmax = m;
      #pragma unroll
      for (int s = 32; s; s >>= 1) {
        unsigned int o = (unsigned int)__shfl_xor((int)wmax, s, 64);
        wmax = (o > wmax) ? o : wmax;
      }
      T = wmax;
      if (m == wmax) m = 0;   // ties all removed together -> T only lower
    }
    s_surv[t] = (s16 >= T) ? (u16)1 : (u16)0;
  }
  __syncthreads();

  // 1) read surviving chunks of the row into registers (<= 4 x 16B per thread)
  uint4 raw[4];
  #pragma unroll
  for (int j = 0; j < 4; ++j) {
    bool sv = s_surv[j * 16 + (t >> 4)] != 0;
    if (sv) raw[j] = *(const uint4*)(rowp + j * 2048 + t * 8);
    else    raw[j] = make_uint4(0u, 0u, 0u, 0u);
  }
  __syncthreads();   // vmcnt(0)+barrier: ALL reads done before ANY zero-store

  // 2) zero the f32 output row (nontemporal: don't evict L3-resident S).
  {
    float* oro = adj + (size_t)r * N_TOT;
    const f32x4 z4 = (f32x4){0.f, 0.f, 0.f, 0.f};
    #pragma unroll
    for (int kk = 0; kk < 8; ++kk)
      __builtin_nontemporal_store(z4, (f32x4*)(oro + kk * 1024 + t * 4));
  }

  // 3) packed keys: high16 = sortable bf16, low13 = 8191-col. Pruned -> 0.
  unsigned int keys[32];
  #pragma unroll
  for (int j = 0; j < 4; ++j) {
    int c0 = j * 2048 + t * 8;
    bool sv = s_surv[j * 16 + (t >> 4)] != 0;
    u16 e[8]; *(uint4*)e = raw[j];
    #pragma unroll
    for (int q = 0; q < 8; ++q) {
      int col = c0 + q;
      unsigned int k = 0;
      if (sv) {
        unsigned int b = e[q];
        unsigned int s16 = (b & 0x8000u) ? (b ^ 0xFFFFu) : (b | 0x8000u);
        k = (s16 << 16) | (unsigned int)(8191 - col);
      }
      if (col == r) k = 0xFFFF0000u | (unsigned int)(8191 - r);  // forced max
      keys[j * 8 + q] = k;
    }
  }

  // 4) per-thread top-2 (with slot indices)
  unsigned int m1 = 0, m2 = 0; int i1 = 0, i2 = 0;
  #pragma unroll
  for (int i = 0; i < 32; ++i) {
    unsigned int k = keys[i];
    if (k > m1) { m2 = m1; i2 = i1; m1 = k; i1 = i; }
    else if (k > m2) { m2 = k; i2 = i; }
  }
  unsigned int taken = 0;

  // 5) wave-local top-16, zero barriers, zero LDS traffic in the loop
  for (int it = 0; it < KSEL; ++it) {
    unsigned int wmax = m1;
    #pragma unroll
    for (int s = 32; s; s >>= 1) {
      unsigned int o = (unsigned int)__shfl_xor((int)wmax, s, 64);
      wmax = (o > wmax) ? o : wmax;
    }
    if (lane == it) cand[wave * 16 + it] = wmax;
    if (m1 == wmax && m1 != 0) {          // unique owner (keys unique)
      taken |= 1u << i1;
      if (m2 != 0) { m1 = m2; i1 = i2; m2 = 0; }
      else {                               // masked in-register rescan
        m1 = 0; m2 = 0; i1 = 0; i2 = 0;
        #pragma unroll
        for (int i = 0; i < 32; ++i) {
          unsigned int k = (taken & (1u << i)) ? 0u : keys[i];
          if (k > m1) { m2 = m1; i2 = i1; m1 = k; i1 = i; }
          else if (k > m2) { m2 = k; i2 = i; }
        }
      }
    }
  }
  __syncthreads();

  // 6) wave 0 merges 64 candidates -> global top-16, writes outputs
  if (wave == 0) {
    unsigned int c = cand[lane];
    unsigned int myWin = 0;
    for (int it = 0; it < KSEL; ++it) {
      unsigned int wmax = c;
      #pragma unroll
      for (int s = 32; s; s >>= 1) {
        unsigned int o = (unsigned int)__shfl_xor((int)wmax, s, 64);
        wmax = (o > wmax) ? o : wmax;
      }
      if (c == wmax) c = 0;
      if (lane == it) myWin = wmax;
    }
    float val = 0.f;
    int col = 0;
    if (lane < KSEL) {
      unsigned int p = myWin;
      col = 8191 - (int)(p & 0x1FFFu);
      unsigned int k16 = p >> 16;
      unsigned int b = (k16 & 0x8000u) ? (k16 ^ 0x8000u) : ((~k16) & 0xFFFFu);
      val = (col == r) ? s_diag : bf2f((u16)b);
      topk_idx[r * KSEL + lane] = col;
      topk_val[r * KSEL + lane] = val;
    }
    float s = (lane < KSEL) ? val : 0.f;
    #pragma unroll
    for (int m = 8; m; m >>= 1) s += __shfl_xor(s, m, 64);
    if (lane == 0) deg_out[r] = s;
  }
}

// K5: scatter the 16 scaled entries per row (zeros already written by k_topk).
__global__ void k_scale(float* __restrict__ adj, const int* __restrict__ topk_idx,
                        const float* __restrict__ topk_val,
                        const float* __restrict__ deg) {
  int g = blockIdx.x * blockDim.x + threadIdx.x;
  if (g >= N_TOT * KSEL) return;
  int r = g >> 4, m = g & 15;
  int j = topk_idx[r * KSEL + m];
  if (j < 0) j = 0; if (j >= N_TOT) j = N_TOT - 1;   // insurance
  float v = topk_val[r * KSEL + m];
  float di = 1.0f / sqrtf(fmaxf(deg[r], 1e-12f));
  float dj = 1.0f / sqrtf(fmaxf(deg[j], 1e-12f));
  adj[(size_t)r * N_TOT + j] = v * di * dj;
}

extern "C" void kernel_launch(void* const* d_in, const int* in_sizes, int n_in,
                              void* d_out, int out_size, void* d_ws, size_t ws_size,
                              hipStream_t stream) {
  const float* feats   = (const float*)d_in[0];
  const float* coords  = (const float*)d_in[1];
  const float* hfeats  = (const float*)d_in[2];
  const float* hcoords = (const float*)d_in[3];
  float* out    = (float*)d_out;
  float* adj    = out;                               // [8192, 8192] f32
  u16*   adj16  = (u16*)out;                         // bf16 S packed per-row
  float* out_nf = out + (size_t)N_TOT * N_TOT;       // [8192, 256]  f32

  char* ws    = (char*)d_ws;
  u16*  Zb    = (u16*)ws;
  size_t zb   = (size_t)N_TOT * C_TOT * sizeof(u16);
  zb = (zb + 255) & ~(size_t)255;
  int*   t_idx = (int*)(ws + zb);
  float* t_val = (float*)(ws + zb + (size_t)N_TOT*KSEL*sizeof(int));
  float* deg   = (float*)(ws + zb + (size_t)N_TOT*KSEL*(sizeof(int)+sizeof(float)));
  u16*   smax  = (u16*)(ws + zb + (size_t)N_TOT*KSEL*(sizeof(int)+sizeof(float))
                                + (size_t)N_TOT*sizeof(float));   // [8192][64] bf16

  hipLaunchKernelGGL(k_prep, dim3(N_TOT/4), dim3(256), 0, stream,
                     feats, hfeats, coords, hcoords, Zb, out_nf);
  hipLaunchKernelGGL(k_gemm_mfma, dim3(NTILE*(NTILE+1)/2), dim3(256), 0, stream,
                     Zb, adj16, smax);
  hipLaunchKernelGGL(k_topk, dim3(N_TOT), dim3(256), 0, stream,
                     adj16, adj, smax, t_idx, t_val, deg);
  hipLaunchKernelGGL(k_scale, dim3((N_TOT*KSEL + 255)/256), dim3(256), 0, stream,
                     adj, t_idx, t_val, deg);
}

// Round 4
// 402.880 us; speedup vs baseline: 1.0291x; 1.0291x over previous
//
#include <hip/hip_runtime.h>
#include <math.h>

#define B_CUR 4096
#define N_TOT 8192
#define C_F   256
#define C_TOT 288
#define KSEL  16
#define NTILE 64    // 8192 / 128

typedef unsigned short u16;
typedef __attribute__((ext_vector_type(8))) short short8;
typedef __attribute__((ext_vector_type(4))) float floatx4;
typedef __attribute__((ext_vector_type(4))) float f32x4;

__device__ inline float bf2f(u16 v) {
  union { unsigned int u; float f; } x; x.u = ((unsigned int)v) << 16; return x.f;
}
__device__ inline u16 f2bf(float f) {
  union { float f; unsigned int u; } x; x.f = f;
  unsigned int u = x.u;
  u += ((u >> 16) & 1u) + 0x7FFFu;   // RNE
  return (u16)(u >> 16);
}

#define GLD_LDS16(g, l) __builtin_amdgcn_global_load_lds(                      \
    (const __attribute__((address_space(1))) unsigned int*)(g),                \
    (__attribute__((address_space(3))) unsigned int*)(l), 16, 0, 0)

// K1 (fused): per wave = one row. Feature normalize (64 lanes) + PE (32 lanes).
__global__ __launch_bounds__(256) void k_prep(
    const float* __restrict__ feats, const float* __restrict__ hfeats,
    const float* __restrict__ coords, const float* __restrict__ hcoords,
    u16* __restrict__ Zb, float* __restrict__ out_nf) {
  int wave = threadIdx.x >> 6;
  int lane = threadIdx.x & 63;
  int row  = blockIdx.x * 4 + wave;
  const float* src = (row < B_CUR) ? (feats + (size_t)row * C_F)
                                   : (hfeats + (size_t)(row - B_CUR) * C_F);
  int c0 = lane * 4;
  float4 raw = *(const float4*)(src + c0);
  float ss = raw.x*raw.x + raw.y*raw.y + raw.z*raw.z + raw.w*raw.w;
  #pragma unroll
  for (int m = 32; m; m >>= 1) ss += __shfl_xor(ss, m, 64);
  float scale = 0.97467943448089633f / fmaxf(sqrtf(ss), 1e-12f);   // sqrt(0.95)
  ushort4 o;
  o.x = f2bf(raw.x*scale); o.y = f2bf(raw.y*scale);
  o.z = f2bf(raw.z*scale); o.w = f2bf(raw.w*scale);
  *(ushort4*)(Zb + (size_t)row * C_TOT + c0) = o;
  *(float4*)(out_nf + (size_t)row * C_F + c0) = raw;

  const float* csrc = (row < B_CUR) ? (coords + (size_t)row * 4)
                                    : (hcoords + (size_t)(row - B_CUR) * 4);
  int d = lane >> 3, sc = (lane >> 2) & 1, f = lane & 3;
  float c = csrc[d & 3];
  float ang = c * 6.283185307179586f * (float)(1 << f);
  float pe = sc ? cosf(ang) : sinf(ang);
  float p2 = pe * pe;
  #pragma unroll
  for (int m = 16; m; m >>= 1) p2 += __shfl_xor(p2, m, 64);
  float pscale = 0.22360679774997896f / fmaxf(sqrtf(p2), 1e-12f); // sqrt(0.05)
  if (lane < 32) Zb[(size_t)row * C_TOT + C_F + lane] = f2bf(pe * pscale);
}

// K3: S = Zb Zb^T, symmetric: upper-triangle tiles only, mirrored epilogue.
// (Round-0 exact form: stride 96 is conflict-free for this read pattern.)
#define EP_STRIDE 136
__global__ __launch_bounds__(256) void k_gemm_mfma(const u16* __restrict__ Zb,
                                                   u16* __restrict__ adj16) {
  __shared__ __align__(16) u16 smem[2 * 128 * 96];     // 49152 B
  u16* As = smem;
  u16* Bs = smem + 128 * 96;
  int tid  = threadIdx.x;

  int t = blockIdx.x;
  int bi = (int)floorf(((2.0f*NTILE + 1.0f) -
            sqrtf((float)((2*NTILE+1)*(2*NTILE+1)) - 8.0f*(float)t)) * 0.5f);
  if (bi < 0) bi = 0; if (bi > NTILE-1) bi = NTILE-1;
  while (bi > 0 && t < bi*NTILE - bi*(bi-1)/2) --bi;
  while (bi < NTILE-1 && t >= (bi+1)*NTILE - (bi+1)*bi/2) ++bi;
  int bj = bi + (t - (bi*NTILE - bi*(bi-1)/2));

  int wave = tid >> 6, lane = tid & 63;
  int quad = lane >> 4, l16 = lane & 15;
  int m0w  = (wave >> 1) * 64;
  int n0w  = (wave & 1) * 64;
  int i0   = bi * 128, j0 = bj * 128;

  floatx4 acc[4][4];
  #pragma unroll
  for (int a = 0; a < 4; ++a)
    #pragma unroll
    for (int b = 0; b < 4; ++b) acc[a][b] = (floatx4){0.f, 0.f, 0.f, 0.f};

  for (int kt = 0; kt < C_TOT; kt += 96) {
    #pragma unroll
    for (int it = 0; it < 6; ++it) {
      int s   = it * 256 + tid;
      int row = s / 12, seg = s % 12;
      const u16* ga = Zb + (size_t)(i0 + row) * C_TOT + kt + seg * 8;
      const u16* gb = Zb + (size_t)(j0 + row) * C_TOT + kt + seg * 8;
      GLD_LDS16(ga, As + s * 8);
      GLD_LDS16(gb, Bs + s * 8);
    }
    __builtin_amdgcn_s_waitcnt(0);
    __syncthreads();
    #pragma unroll
    for (int ks = 0; ks < 3; ++ks) {
      short8 af[4], bf[4];
      #pragma unroll
      for (int mi = 0; mi < 4; ++mi)
        af[mi] = *(const short8*)(&As[(m0w + mi*16 + l16) * 96 + ks*32 + quad*8]);
      #pragma unroll
      for (int ni = 0; ni < 4; ++ni)
        bf[ni] = *(const short8*)(&Bs[(n0w + ni*16 + l16) * 96 + ks*32 + quad*8]);
      #pragma unroll
      for (int mi = 0; mi < 4; ++mi)
        #pragma unroll
        for (int ni = 0; ni < 4; ++ni)
          acc[mi][ni] = __builtin_amdgcn_mfma_f32_16x16x32_bf16(
              af[mi], bf[ni], acc[mi][ni], 0, 0, 0);
    }
    __syncthreads();
  }

  float w = ((bi < 32) != (bj < 32)) ? 0.5f : 1.0f;

  #pragma unroll
  for (int mi = 0; mi < 4; ++mi) {
    #pragma unroll
    for (int ni = 0; ni < 4; ++ni) {
      int col = n0w + ni * 16 + l16;
      #pragma unroll
      for (int rg = 0; rg < 4; ++rg) {
        int row = m0w + mi * 16 + quad * 4 + rg;
        smem[row * EP_STRIDE + col] = f2bf(acc[mi][ni][rg] * w);
      }
    }
  }
  __syncthreads();
  #pragma unroll
  for (int it = 0; it < 8; ++it) {
    int idx = it * 256 + tid;
    int row = idx >> 4, l = idx & 15;
    uint4 v = *(const uint4*)(&smem[row * EP_STRIDE + l * 8]);
    *(uint4*)(&adj16[(size_t)(i0 + row) * 16384 + j0 + l * 8]) = v;
  }

  if (bi != bj) {
    __syncthreads();
    #pragma unroll
    for (int mi = 0; mi < 4; ++mi) {
      #pragma unroll
      for (int ni = 0; ni < 4; ++ni) {
        int col = n0w + ni * 16 + l16;
        #pragma unroll
        for (int rg = 0; rg < 4; ++rg) {
          int row = m0w + mi * 16 + quad * 4 + rg;
          smem[col * EP_STRIDE + row] = f2bf(acc[mi][ni][rg] * w);
        }
      }
    }
    __syncthreads();
    #pragma unroll
    for (int it = 0; it < 8; ++it) {
      int idx = it * 256 + tid;
      int row = idx >> 4, l = idx & 15;
      uint4 v = *(const uint4*)(&smem[row * EP_STRIDE + l * 8]);
      *(uint4*)(&adj16[(size_t)(j0 + row) * 16384 + i0 + l * 8]) = v;
    }
  }
}

// K4: per-row top-16, PURE READ + register-resident selection. No adj writes
//     here: keeping this pass read-only means L3 holds only S (134 MB <= 256)
//     while it runs -> reads stay cache-hits instead of racing the zero-write
//     stream for L3 capacity. Outputs only idx/val/deg (1 MB).
__global__ __launch_bounds__(256) void k_topk(
    const u16* __restrict__ adj16,
    int* __restrict__ topk_idx, float* __restrict__ topk_val,
    float* __restrict__ deg_out) {
  __shared__ unsigned int cand[64];
  __shared__ float s_diag;
  int r = blockIdx.x;
  int t = threadIdx.x;
  int wave = t >> 6, lane = t & 63;
  const u16* rowp = adj16 + (size_t)r * 16384;

  // 1) read the whole row into registers (4 x 16B per thread) + diag
  uint4 raw[4];
  #pragma unroll
  for (int j = 0; j < 4; ++j)
    raw[j] = *(const uint4*)(rowp + j * 2048 + t * 8);
  if (t == 0) s_diag = bf2f(rowp[r]);

  // 2) build packed keys in registers.
  //    key: high16 = sortable bf16, low13 = 8191-col (lowest col wins ties)
  unsigned int keys[32];
  #pragma unroll
  for (int j = 0; j < 4; ++j) {
    int c0 = j * 2048 + t * 8;
    u16 e[8]; *(uint4*)e = raw[j];
    #pragma unroll
    for (int q = 0; q < 8; ++q) {
      int col = c0 + q;
      unsigned int b = e[q];
      unsigned int s16 = (b & 0x8000u) ? (b ^ 0xFFFFu) : (b | 0x8000u);
      unsigned int k = (s16 << 16) | (unsigned int)(8191 - col);
      if (col == r) k = 0xFFFF0000u | (unsigned int)(8191 - r);  // forced max
      keys[j * 8 + q] = k;
    }
  }

  // 3) per-thread top-2 (with slot indices)
  unsigned int m1 = 0, m2 = 0; int i1 = 0, i2 = 0;
  #pragma unroll
  for (int i = 0; i < 32; ++i) {
    unsigned int k = keys[i];
    if (k > m1) { m2 = m1; i2 = i1; m1 = k; i1 = i; }
    else if (k > m2) { m2 = k; i2 = i; }
  }
  unsigned int taken = 0;

  // 4) wave-local top-16, zero barriers, zero LDS traffic in the loop
  for (int it = 0; it < KSEL; ++it) {
    unsigned int wmax = m1;
    #pragma unroll
    for (int s = 32; s; s >>= 1) {
      unsigned int o = (unsigned int)__shfl_xor((int)wmax, s, 64);
      wmax = (o > wmax) ? o : wmax;
    }
    if (lane == it) cand[wave * 16 + it] = wmax;
    if (m1 == wmax && m1 != 0) {          // unique owner (keys unique)
      taken |= 1u << i1;
      if (m2 != 0) { m1 = m2; i1 = i2; m2 = 0; }
      else {                               // masked in-register rescan
        m1 = 0; m2 = 0; i1 = 0; i2 = 0;
        #pragma unroll
        for (int i = 0; i < 32; ++i) {
          unsigned int k = (taken & (1u << i)) ? 0u : keys[i];
          if (k > m1) { m2 = m1; i2 = i1; m1 = k; i1 = i; }
          else if (k > m2) { m2 = k; i2 = i; }
        }
      }
    }
  }
  __syncthreads();

  // 5) wave 0 merges 64 candidates -> global top-16, writes outputs
  if (wave == 0) {
    unsigned int c = cand[lane];
    unsigned int myWin = 0;
    for (int it = 0; it < KSEL; ++it) {
      unsigned int wmax = c;
      #pragma unroll
      for (int s = 32; s; s >>= 1) {
        unsigned int o = (unsigned int)__shfl_xor((int)wmax, s, 64);
        wmax = (o > wmax) ? o : wmax;
      }
      if (c == wmax) c = 0;
      if (lane == it) myWin = wmax;
    }
    float val = 0.f;
    int col = 0;
    if (lane < KSEL) {
      unsigned int p = myWin;
      col = 8191 - (int)(p & 0x1FFFu);
      unsigned int k16 = p >> 16;
      unsigned int b = (k16 & 0x8000u) ? (k16 ^ 0x8000u) : ((~k16) & 0xFFFFu);
      val = (col == r) ? s_diag : bf2f((u16)b);
      topk_idx[r * KSEL + lane] = col;
      topk_val[r * KSEL + lane] = val;
    }
    float s = (lane < KSEL) ? val : 0.f;
    #pragma unroll
    for (int m = 8; m; m >>= 1) s += __shfl_xor(s, m, 64);
    if (lane == 0) deg_out[r] = s;
  }
}

// K5 (k_out): pure unidirectional write pass — zero the f32 row, then patch
//     the 16 scaled entries (lines still L2-hot). Absorbs old k_scale.
//     adj aliases the bf16 S that k_topk read — kernel-serial order is safe.
//     __syncthreads drains each thread's zero-stores (vmcnt(0)+barrier)
//     before any patch store to the same addresses.
__global__ __launch_bounds__(256) void k_out(
    float* adj, const int* __restrict__ topk_idx,
    const float* __restrict__ topk_val, const float* __restrict__ deg) {
  __shared__ float s_val[KSEL];
  __shared__ int   s_col[KSEL];
  int r = blockIdx.x;
  int t = threadIdx.x;
  if (t < KSEL) {
    int j = topk_idx[r * KSEL + t];
    if (j < 0) j = 0; if (j >= N_TOT) j = N_TOT - 1;   // insurance
    float v = topk_val[r * KSEL + t];
    float di = 1.0f / sqrtf(fmaxf(deg[r], 1e-12f));
    float dj = 1.0f / sqrtf(fmaxf(deg[j], 1e-12f));
    s_col[t] = j;
    s_val[t] = v * di * dj;
  }
  float* row = adj + (size_t)r * N_TOT;
  const f32x4 z4 = (f32x4){0.f, 0.f, 0.f, 0.f};
  #pragma unroll
  for (int kk = 0; kk < 8; ++kk)
    *(f32x4*)(row + kk * 1024 + t * 4) = z4;
  __syncthreads();   // all zero-stores drained block-wide before patches
  if (t < KSEL) row[s_col[t]] = s_val[t];
}

extern "C" void kernel_launch(void* const* d_in, const int* in_sizes, int n_in,
                              void* d_out, int out_size, void* d_ws, size_t ws_size,
                              hipStream_t stream) {
  const float* feats   = (const float*)d_in[0];
  const float* coords  = (const float*)d_in[1];
  const float* hfeats  = (const float*)d_in[2];
  const float* hcoords = (const float*)d_in[3];
  float* out    = (float*)d_out;
  float* adj    = out;                               // [8192, 8192] f32
  u16*   adj16  = (u16*)out;                         // bf16 S packed per-row
  float* out_nf = out + (size_t)N_TOT * N_TOT;       // [8192, 256]  f32

  char* ws    = (char*)d_ws;
  u16*  Zb    = (u16*)ws;
  size_t zb   = (size_t)N_TOT * C_TOT * sizeof(u16);
  zb = (zb + 255) & ~(size_t)255;
  int*   t_idx = (int*)(ws + zb);
  float* t_val = (float*)(ws + zb + (size_t)N_TOT*KSEL*sizeof(int));
  float* deg   = (float*)(ws + zb + (size_t)N_TOT*KSEL*(sizeof(int)+sizeof(float)));

  hipLaunchKernelGGL(k_prep, dim3(N_TOT/4), dim3(256), 0, stream,
                     feats, hfeats, coords, hcoords, Zb, out_nf);
  hipLaunchKernelGGL(k_gemm_mfma, dim3(NTILE*(NTILE+1)/2), dim3(256), 0, stream,
                     Zb, adj16);
  hipLaunchKernelGGL(k_topk, dim3(N_TOT), dim3(256), 0, stream,
                     adj16, t_idx, t_val, deg);
  hipLaunchKernelGGL(k_out, dim3(N_TOT), dim3(256), 0, stream,
                     adj, t_idx, t_val, deg);
}

// Round 5
// 382.997 us; speedup vs baseline: 1.0825x; 1.0519x over previous
//
#include <hip/hip_runtime.h>
#include <math.h>

#define B_CUR 4096
#define N_TOT 8192
#define C_F   256
#define C_TOT 288
#define KSEL  16
#define NTILE 64    // 8192 / 128

typedef unsigned short u16;
typedef __attribute__((ext_vector_type(8))) short short8;
typedef __attribute__((ext_vector_type(4))) float floatx4;

__device__ inline float bf2f(u16 v) {
  union { unsigned int u; float f; } x; x.u = ((unsigned int)v) << 16; return x.f;
}
__device__ inline u16 f2bf(float f) {
  union { float f; unsigned int u; } x; x.f = f;
  unsigned int u = x.u;
  u += ((u >> 16) & 1u) + 0x7FFFu;   // RNE
  return (u16)(u >> 16);
}

#define GLD_LDS16(g, l) __builtin_amdgcn_global_load_lds(                      \
    (const __attribute__((address_space(1))) unsigned int*)(g),                \
    (__attribute__((address_space(3))) unsigned int*)(l), 16, 0, 0)

// K1 (fused): per wave = one row. Feature normalize (64 lanes) + PE (32 lanes).
__global__ __launch_bounds__(256) void k_prep(
    const float* __restrict__ feats, const float* __restrict__ hfeats,
    const float* __restrict__ coords, const float* __restrict__ hcoords,
    u16* __restrict__ Zb, float* __restrict__ out_nf) {
  int wave = threadIdx.x >> 6;
  int lane = threadIdx.x & 63;
  int row  = blockIdx.x * 4 + wave;
  const float* src = (row < B_CUR) ? (feats + (size_t)row * C_F)
                                   : (hfeats + (size_t)(row - B_CUR) * C_F);
  int c0 = lane * 4;
  float4 raw = *(const float4*)(src + c0);
  float ss = raw.x*raw.x + raw.y*raw.y + raw.z*raw.z + raw.w*raw.w;
  #pragma unroll
  for (int m = 32; m; m >>= 1) ss += __shfl_xor(ss, m, 64);
  float scale = 0.97467943448089633f / fmaxf(sqrtf(ss), 1e-12f);   // sqrt(0.95)
  ushort4 o;
  o.x = f2bf(raw.x*scale); o.y = f2bf(raw.y*scale);
  o.z = f2bf(raw.z*scale); o.w = f2bf(raw.w*scale);
  *(ushort4*)(Zb + (size_t)row * C_TOT + c0) = o;
  *(float4*)(out_nf + (size_t)row * C_F + c0) = raw;

  const float* csrc = (row < B_CUR) ? (coords + (size_t)row * 4)
                                    : (hcoords + (size_t)(row - B_CUR) * 4);
  int d = lane >> 3, sc = (lane >> 2) & 1, f = lane & 3;
  float c = csrc[d & 3];
  float ang = c * 6.283185307179586f * (float)(1 << f);
  float pe = sc ? cosf(ang) : sinf(ang);
  float p2 = pe * pe;
  #pragma unroll
  for (int m = 16; m; m >>= 1) p2 += __shfl_xor(p2, m, 64);
  float pscale = 0.22360679774997896f / fmaxf(sqrtf(p2), 1e-12f); // sqrt(0.05)
  if (lane < 32) Zb[(size_t)row * C_TOT + C_F + lane] = f2bf(pe * pscale);
}

// K3: S = Zb Zb^T, symmetric: upper-triangle tiles only, mirrored epilogue.
#define EP_STRIDE 136
__global__ __launch_bounds__(256) void k_gemm_mfma(const u16* __restrict__ Zb,
                                                   u16* __restrict__ adj16) {
  __shared__ __align__(16) u16 smem[2 * 128 * 96];     // 49152 B
  u16* As = smem;
  u16* Bs = smem + 128 * 96;
  int tid  = threadIdx.x;

  int t = blockIdx.x;
  int bi = (int)floorf(((2.0f*NTILE + 1.0f) -
            sqrtf((float)((2*NTILE+1)*(2*NTILE+1)) - 8.0f*(float)t)) * 0.5f);
  if (bi < 0) bi = 0; if (bi > NTILE-1) bi = NTILE-1;
  while (bi > 0 && t < bi*NTILE - bi*(bi-1)/2) --bi;
  while (bi < NTILE-1 && t >= (bi+1)*NTILE - (bi+1)*bi/2) ++bi;
  int bj = bi + (t - (bi*NTILE - bi*(bi-1)/2));

  int wave = tid >> 6, lane = tid & 63;
  int quad = lane >> 4, l16 = lane & 15;
  int m0w  = (wave >> 1) * 64;
  int n0w  = (wave & 1) * 64;
  int i0   = bi * 128, j0 = bj * 128;

  floatx4 acc[4][4];
  #pragma unroll
  for (int a = 0; a < 4; ++a)
    #pragma unroll
    for (int b = 0; b < 4; ++b) acc[a][b] = (floatx4){0.f, 0.f, 0.f, 0.f};

  for (int kt = 0; kt < C_TOT; kt += 96) {
    #pragma unroll
    for (int it = 0; it < 6; ++it) {
      int s   = it * 256 + tid;
      int row = s / 12, seg = s % 12;
      const u16* ga = Zb + (size_t)(i0 + row) * C_TOT + kt + seg * 8;
      const u16* gb = Zb + (size_t)(j0 + row) * C_TOT + kt + seg * 8;
      GLD_LDS16(ga, As + s * 8);
      GLD_LDS16(gb, Bs + s * 8);
    }
    __builtin_amdgcn_s_waitcnt(0);
    __syncthreads();
    #pragma unroll
    for (int ks = 0; ks < 3; ++ks) {
      short8 af[4], bf[4];
      #pragma unroll
      for (int mi = 0; mi < 4; ++mi)
        af[mi] = *(const short8*)(&As[(m0w + mi*16 + l16) * 96 + ks*32 + quad*8]);
      #pragma unroll
      for (int ni = 0; ni < 4; ++ni)
        bf[ni] = *(const short8*)(&Bs[(n0w + ni*16 + l16) * 96 + ks*32 + quad*8]);
      #pragma unroll
      for (int mi = 0; mi < 4; ++mi)
        #pragma unroll
        for (int ni = 0; ni < 4; ++ni)
          acc[mi][ni] = __builtin_amdgcn_mfma_f32_16x16x32_bf16(
              af[mi], bf[ni], acc[mi][ni], 0, 0, 0);
    }
    __syncthreads();
  }

  float w = ((bi < 32) != (bj < 32)) ? 0.5f : 1.0f;

  #pragma unroll
  for (int mi = 0; mi < 4; ++mi) {
    #pragma unroll
    for (int ni = 0; ni < 4; ++ni) {
      int col = n0w + ni * 16 + l16;
      #pragma unroll
      for (int rg = 0; rg < 4; ++rg) {
        int row = m0w + mi * 16 + quad * 4 + rg;
        smem[row * EP_STRIDE + col] = f2bf(acc[mi][ni][rg] * w);
      }
    }
  }
  __syncthreads();
  #pragma unroll
  for (int it = 0; it < 8; ++it) {
    int idx = it * 256 + tid;
    int row = idx >> 4, l = idx & 15;
    uint4 v = *(const uint4*)(&smem[row * EP_STRIDE + l * 8]);
    *(uint4*)(&adj16[(size_t)(i0 + row) * 16384 + j0 + l * 8]) = v;
  }

  if (bi != bj) {
    __syncthreads();
    #pragma unroll
    for (int mi = 0; mi < 4; ++mi) {
      #pragma unroll
      for (int ni = 0; ni < 4; ++ni) {
        int col = n0w + ni * 16 + l16;
        #pragma unroll
        for (int rg = 0; rg < 4; ++rg) {
          int row = m0w + mi * 16 + quad * 4 + rg;
          smem[col * EP_STRIDE + row] = f2bf(acc[mi][ni][rg] * w);
        }
      }
    }
    __syncthreads();
    #pragma unroll
    for (int it = 0; it < 8; ++it) {
      int idx = it * 256 + tid;
      int row = idx >> 4, l = idx & 15;
      uint4 v = *(const uint4*)(&smem[row * EP_STRIDE + l * 8]);
      *(uint4*)(&adj16[(size_t)(j0 + row) * 16384 + i0 + l * 8]) = v;
    }
  }
}

// K4: per-row top-16, register-resident selection. adj16/adj ALIAS (same buffer):
//     no __restrict__ on them, and a __syncthreads() separates the row reads
//     (into registers) from the f32 zero-stores — loads drained block-wide first.
__global__ __launch_bounds__(256) void k_topk(
    const u16* adj16, float* adj,
    int* __restrict__ topk_idx, float* __restrict__ topk_val,
    float* __restrict__ deg_out) {
  __shared__ unsigned int cand[64];
  __shared__ float s_diag;
  int r = blockIdx.x;
  int t = threadIdx.x;
  int wave = t >> 6, lane = t & 63;
  const u16* rowp = adj16 + (size_t)r * 16384;

  // 1) read the whole row into registers (4 x 16B per thread) + diag
  uint4 raw[4];
  #pragma unroll
  for (int j = 0; j < 4; ++j)
    raw[j] = *(const uint4*)(rowp + j * 2048 + t * 8);
  if (t == 0) s_diag = bf2f(rowp[r]);
  __syncthreads();   // vmcnt(0)+barrier: ALL reads done before ANY zero-store

  // 2) zero the f32 output row; stores drain during register-only selection.
  {
    float* oro = adj + (size_t)r * N_TOT;
    const float4 z4 = make_float4(0.f, 0.f, 0.f, 0.f);
    #pragma unroll
    for (int kk = 0; kk < 8; ++kk)
      *(float4*)(oro + kk * 1024 + t * 4) = z4;
  }

  // 3) build packed keys in registers.
  //    key: high16 = sortable bf16, low13 = 8191-col (lowest col wins ties)
  unsigned int keys[32];
  #pragma unroll
  for (int j = 0; j < 4; ++j) {
    int c0 = j * 2048 + t * 8;
    u16 e[8]; *(uint4*)e = raw[j];
    #pragma unroll
    for (int q = 0; q < 8; ++q) {
      int col = c0 + q;
      unsigned int b = e[q];
      unsigned int s16 = (b & 0x8000u) ? (b ^ 0xFFFFu) : (b | 0x8000u);
      unsigned int k = (s16 << 16) | (unsigned int)(8191 - col);
      if (col == r) k = 0xFFFF0000u | (unsigned int)(8191 - r);  // forced max
      keys[j * 8 + q] = k;
    }
  }

  // 4) per-thread top-2 (with slot indices)
  unsigned int m1 = 0, m2 = 0; int i1 = 0, i2 = 0;
  #pragma unroll
  for (int i = 0; i < 32; ++i) {
    unsigned int k = keys[i];
    if (k > m1) { m2 = m1; i2 = i1; m1 = k; i1 = i; }
    else if (k > m2) { m2 = k; i2 = i; }
  }
  unsigned int taken = 0;

  // 5) wave-local top-16, zero barriers, zero LDS traffic in the loop
  for (int it = 0; it < KSEL; ++it) {
    unsigned int wmax = m1;
    #pragma unroll
    for (int s = 32; s; s >>= 1) {
      unsigned int o = (unsigned int)__shfl_xor((int)wmax, s, 64);
      wmax = (o > wmax) ? o : wmax;
    }
    if (lane == it) cand[wave * 16 + it] = wmax;
    if (m1 == wmax && m1 != 0) {          // unique owner (keys unique)
      taken |= 1u << i1;
      if (m2 != 0) { m1 = m2; i1 = i2; m2 = 0; }
      else {                               // masked in-register rescan
        m1 = 0; m2 = 0; i1 = 0; i2 = 0;
        #pragma unroll
        for (int i = 0; i < 32; ++i) {
          unsigned int k = (taken & (1u << i)) ? 0u : keys[i];
          if (k > m1) { m2 = m1; i2 = i1; m1 = k; i1 = i; }
          else if (k > m2) { m2 = k; i2 = i; }
        }
      }
    }
  }
  __syncthreads();

  // 6) wave 0 merges 64 candidates -> global top-16, writes outputs
  if (wave == 0) {
    unsigned int c = cand[lane];
    unsigned int myWin = 0;
    for (int it = 0; it < KSEL; ++it) {
      unsigned int wmax = c;
      #pragma unroll
      for (int s = 32; s; s >>= 1) {
        unsigned int o = (unsigned int)__shfl_xor((int)wmax, s, 64);
        wmax = (o > wmax) ? o : wmax;
      }
      if (c == wmax) c = 0;
      if (lane == it) myWin = wmax;
    }
    float val = 0.f;
    int col = 0;
    if (lane < KSEL) {
      unsigned int p = myWin;
      col = 8191 - (int)(p & 0x1FFFu);
      unsigned int k16 = p >> 16;
      unsigned int b = (k16 & 0x8000u) ? (k16 ^ 0x8000u) : ((~k16) & 0xFFFFu);
      val = (col == r) ? s_diag : bf2f((u16)b);
      topk_idx[r * KSEL + lane] = col;
      topk_val[r * KSEL + lane] = val;
    }
    float s = (lane < KSEL) ? val : 0.f;
    #pragma unroll
    for (int m = 8; m; m >>= 1) s += __shfl_xor(s, m, 64);
    if (lane == 0) deg_out[r] = s;
  }
}

// K5: scatter the 16 scaled entries per row (zeros already written by k_topk).
__global__ void k_scale(float* __restrict__ adj, const int* __restrict__ topk_idx,
                        const float* __restrict__ topk_val,
                        const float* __restrict__ deg) {
  int g = blockIdx.x * blockDim.x + threadIdx.x;
  if (g >= N_TOT * KSEL) return;
  int r = g >> 4, m = g & 15;
  int j = topk_idx[r * KSEL + m];
  if (j < 0) j = 0; if (j >= N_TOT) j = N_TOT - 1;   // insurance
  float v = topk_val[r * KSEL + m];
  float di = 1.0f / sqrtf(fmaxf(deg[r], 1e-12f));
  float dj = 1.0f / sqrtf(fmaxf(deg[j], 1e-12f));
  adj[(size_t)r * N_TOT + j] = v * di * dj;
}

extern "C" void kernel_launch(void* const* d_in, const int* in_sizes, int n_in,
                              void* d_out, int out_size, void* d_ws, size_t ws_size,
                              hipStream_t stream) {
  const float* feats   = (const float*)d_in[0];
  const float* coords  = (const float*)d_in[1];
  const float* hfeats  = (const float*)d_in[2];
  const float* hcoords = (const float*)d_in[3];
  float* out    = (float*)d_out;
  float* adj    = out;                               // [8192, 8192] f32
  u16*   adj16  = (u16*)out;                         // bf16 S packed per-row
  float* out_nf = out + (size_t)N_TOT * N_TOT;       // [8192, 256]  f32

  char* ws    = (char*)d_ws;
  u16*  Zb    = (u16*)ws;
  size_t zb   = (size_t)N_TOT * C_TOT * sizeof(u16);
  zb = (zb + 255) & ~(size_t)255;
  int*   t_idx = (int*)(ws + zb);
  float* t_val = (float*)(ws + zb + (size_t)N_TOT*KSEL*sizeof(int));
  float* deg   = (float*)(ws + zb + (size_t)N_TOT*KSEL*(sizeof(int)+sizeof(float)));

  hipLaunchKernelGGL(k_prep, dim3(N_TOT/4), dim3(256), 0, stream,
                     feats, hfeats, coords, hcoords, Zb, out_nf);
  hipLaunchKernelGGL(k_gemm_mfma, dim3(NTILE*(NTILE+1)/2), dim3(256), 0, stream,
                     Zb, adj16);
  hipLaunchKernelGGL(k_topk, dim3(N_TOT), dim3(256), 0, stream,
                     adj16, adj, t_idx, t_val, deg);
  hipLaunchKernelGGL(k_scale, dim3((N_TOT*KSEL + 255)/256), dim3(256), 0, stream,
                     adj, t_idx, t_val, deg);
}